// Round 1
// 251.497 us; speedup vs baseline: 1.0250x; 1.0250x over previous
//
#include <hip/hip_runtime.h>
#include <stdint.h>

// RelationalNetwork: B=8, C=64, O=256, TE=128, GT=FP=256, A=32
// v2 structure (3 launches):
//   k_pre : W2/W3 transpose->bf16, summed:=0, U/V precompute (q=code.W1q+b1
//           folded in; 8 spatial positions per block for w1 register reuse)
//   k_main: 64-pair tiles (32KiB LDS -> 3 blk/CU), inline (i,j), B-frag
//           prefetch, cvt_pk packing, atomicAdd row-sums into summed
//   k_tail: f_phi on 8 blocks x 1024 threads (4-way k-split per layer)

#define NTILE 514   // 514 * 64 = 32896 = 256*257/2 exactly

using short8  = __attribute__((ext_vector_type(8))) short;
using float4v = __attribute__((ext_vector_type(4))) float;

__device__ __forceinline__ float asf(unsigned u) {
    union { unsigned u; float f; } c; c.u = u; return c.f;
}
__device__ __forceinline__ unsigned short f2bf(float f) {
    union { float f; unsigned u; } c; c.f = f;
    unsigned u = c.u;
    u += 0x7FFFu + ((u >> 16) & 1u);   // RNE
    return (unsigned short)(u >> 16);
}
// packed f32x2 -> bf16x2 (RNE), 1 instr for 2 elements
__device__ __forceinline__ unsigned cvtpk(float lo, float hi) {
    unsigned r;
    asm("v_cvt_pk_bf16_f32 %0, %1, %2" : "=v"(r) : "v"(lo), "v"(hi));
    return r;
}

// ---- fused preprocessing ------------------------------------------------
// grid (33, 8): x<32 -> U/V blocks (ig = x, b = y, 8 spatial positions each)
//               x==32 -> aux: zero summed slice + 4 transpose jobs each
__global__ __launch_bounds__(256) void k_pre(
    const float* __restrict__ x, const float* __restrict__ code,
    const float* __restrict__ w1, const float* __restrict__ b1,
    const float* __restrict__ w2, const float* __restrict__ w3,
    unsigned short* __restrict__ ub, unsigned short* __restrict__ vb,
    unsigned short* __restrict__ w2t, unsigned short* __restrict__ w3t,
    float* __restrict__ summed)
{
    const int tid = threadIdx.x;
    if (blockIdx.x < 32) {
        const int ig = blockIdx.x, b = blockIdx.y, d = tid;
        // q[d] = b1[d] + code . W1[132:260, d]
        float q = b1[d];
        const float* cp = code + b * 128;
        #pragma unroll 8
        for (int t = 0; t < 128; ++t) q += cp[t] * w1[(132 + t) * 256 + d];
        float su[8], sv[8];
        #pragma unroll
        for (int k = 0; k < 8; ++k) { su[k] = q; sv[k] = 0.f; }
        const float* xp = x + (b * 64) * 256 + ig * 8;
        for (int c = 0; c < 64; ++c) {
            const float wu = w1[c * 256 + d];
            const float wv = w1[(66 + c) * 256 + d];
            const float* xc = xp + c * 256;          // uniform -> scalar loads
            #pragma unroll
            for (int k = 0; k < 8; ++k) { su[k] += xc[k] * wu; sv[k] += xc[k] * wv; }
        }
        const float wyu = w1[64 * 256 + d],  wxu = w1[65 * 256 + d];
        const float wyv = w1[130 * 256 + d], wxv = w1[131 * 256 + d];
        #pragma unroll
        for (int k = 0; k < 8; ++k) {
            const int i = ig * 8 + k;
            const float yy = (float)(i >> 4) * (2.0f / 15.0f) - 1.0f;
            const float xx = (float)(i & 15) * (2.0f / 15.0f) - 1.0f;
            ub[(b * 256 + i) * 256 + d] = f2bf(su[k] + yy * wyu + xx * wxu);
            vb[(b * 256 + i) * 256 + d] = f2bf(sv[k] + yy * wyv + xx * wxv);
        }
    } else {
        __shared__ float t[64][65];
        const int y = blockIdx.y;
        summed[y * 256 + tid] = 0.f;                 // zeroed every replay
        const int tx = tid & 63, ty = tid >> 6;
        for (int jj = 0; jj < 4; ++jj) {
            const int job = y * 4 + jj;              // 0..31
            const float* src = (job & 16) ? w3 : w2;
            unsigned short* dst = (job & 16) ? w3t : w2t;
            const int k0 = ((job >> 2) & 3) * 64, n0 = (job & 3) * 64;
            __syncthreads();
            #pragma unroll
            for (int r = ty; r < 64; r += 4) t[r][tx] = src[(k0 + r) * 256 + n0 + tx];
            __syncthreads();
            #pragma unroll
            for (int r = ty; r < 64; r += 4) dst[(n0 + r) * 256 + k0 + tx] = f2bf(t[tx][r]);
        }
    }
}

// ---- fused g_theta L2+L3 + tril row-sum ---------------------------------
// 64-pair tile, LDS 64x256 bf16 = 32KiB -> 3 blocks/CU at launch_bounds(256,3).
// XOR chunk swizzle: element (r,d) at r*256 + (((d>>3) ^ (r&7))<<3 | (d&7)).
__global__ __launch_bounds__(256, 3) void k_main(
    const unsigned short* __restrict__ ub, const unsigned short* __restrict__ vb,
    const unsigned short* __restrict__ w2t, const unsigned short* __restrict__ w3t,
    const float* __restrict__ b2, const float* __restrict__ b3,
    float* __restrict__ summed)
{
    __shared__ unsigned short tile[64 * 256];
    const int tid  = threadIdx.x;
    const int b    = blockIdx.y, tIdx = blockIdx.x;
    const int lane = tid & 63;
    const int wave = tid >> 6;
    const int n0   = wave * 64;           // wave's 64-column slice
    const int lm   = lane & 15, quad = lane >> 4;

    // ---- build h1 = relu(U_i + V_j) into LDS (64 rows, inline i,j) ----
    {
        const int r = tid >> 2, qq = tid & 3;
        const int p = tIdx * 64 + r;
        float s = sqrtf(8.0f * (float)p + 1.0f);
        int i = (int)((s - 1.0f) * 0.5f);
        while ((i + 1) * (i + 2) / 2 <= p) ++i;
        while (i * (i + 1) / 2 > p) --i;
        const int j = p - i * (i + 1) / 2;
        const unsigned short* up = ub + ((b * 256 + i) * 256) + qq * 8;
        const unsigned short* vp = vb + ((b * 256 + j) * 256) + qq * 8;
        const int rs = r & 7;
        #pragma unroll
        for (int it = 0; it < 8; ++it) {
            uint4 uu = *(const uint4*)(up + it * 32);
            uint4 vv = *(const uint4*)(vp + it * 32);
            unsigned ua[4] = {uu.x, uu.y, uu.z, uu.w};
            unsigned va[4] = {vv.x, vv.y, vv.z, vv.w};
            unsigned ra[4];
            #pragma unroll
            for (int qw = 0; qw < 4; ++qw) {
                float lo = asf(ua[qw] << 16)        + asf(va[qw] << 16);
                float hi = asf(ua[qw] & 0xFFFF0000u) + asf(va[qw] & 0xFFFF0000u);
                ra[qw] = cvtpk(fmaxf(lo, 0.f), fmaxf(hi, 0.f));
            }
            const int chunk = qq + it * 4;
            uint4 r4; r4.x = ra[0]; r4.y = ra[1]; r4.z = ra[2]; r4.w = ra[3];
            *(uint4*)(&tile[r * 256 + ((chunk ^ rs) << 3)]) = r4;
        }
    }
    __syncthreads();

    float b2c[4], b3c[4];
    #pragma unroll
    for (int nt = 0; nt < 4; ++nt) {
        b2c[nt] = b2[n0 + nt * 16 + lm];
        b3c[nt] = b3[n0 + nt * 16 + lm];
    }

    const float4v zero4 = {0.f, 0.f, 0.f, 0.f};
    float4v acc[4][4];
    #pragma unroll
    for (int mt = 0; mt < 4; ++mt)
        #pragma unroll
        for (int nt = 0; nt < 4; ++nt) acc[mt][nt] = zero4;

    // ---- GEMM1: h2 = h1 @ W2 (B-frag prefetch double-buffer) ----
    {
        const unsigned short* bb = w2t + (n0 + lm) * 256 + quad * 8;
        short8 bcur[4], bnxt[4];
        #pragma unroll
        for (int nt = 0; nt < 4; ++nt) bcur[nt] = *(const short8*)(bb + nt * 4096);
        for (int ks = 0; ks < 8; ++ks) {
            if (ks < 7) {
                #pragma unroll
                for (int nt = 0; nt < 4; ++nt)
                    bnxt[nt] = *(const short8*)(bb + nt * 4096 + (ks + 1) * 32);
            }
            const int coff = (((ks * 4 + quad) ^ (lane & 7)) << 3);
            short8 afr[4];
            #pragma unroll
            for (int mt = 0; mt < 4; ++mt)
                afr[mt] = *(const short8*)(&tile[(mt * 16 + lm) * 256 + coff]);
            #pragma unroll
            for (int mt = 0; mt < 4; ++mt)
                #pragma unroll
                for (int nt = 0; nt < 4; ++nt)
                    acc[mt][nt] = __builtin_amdgcn_mfma_f32_16x16x32_bf16(
                        afr[mt], bcur[nt], acc[mt][nt], 0, 0, 0);
            #pragma unroll
            for (int nt = 0; nt < 4; ++nt) bcur[nt] = bnxt[nt];
        }
    }
    __syncthreads();

    // ---- h2 = relu(acc + b2) back to LDS (bf16, swizzled, cvt_pk) ----
    #pragma unroll
    for (int mt = 0; mt < 4; ++mt) {
        #pragma unroll
        for (int nt = 0; nt < 4; ++nt) {
            const int col = n0 + nt * 16 + lm;
            const float v0 = fmaxf(acc[mt][nt][0] + b2c[nt], 0.f);
            const float v1 = fmaxf(acc[mt][nt][1] + b2c[nt], 0.f);
            const float v2 = fmaxf(acc[mt][nt][2] + b2c[nt], 0.f);
            const float v3 = fmaxf(acc[mt][nt][3] + b2c[nt], 0.f);
            const unsigned w01 = cvtpk(v0, v1), w23 = cvtpk(v2, v3);
            const int r0 = mt * 16 + quad * 4;
            tile[(r0 + 0) * 256 + ((((col >> 3) ^ ((r0 + 0) & 7)) << 3) | (col & 7))] =
                (unsigned short)w01;
            tile[(r0 + 1) * 256 + ((((col >> 3) ^ ((r0 + 1) & 7)) << 3) | (col & 7))] =
                (unsigned short)(w01 >> 16);
            tile[(r0 + 2) * 256 + ((((col >> 3) ^ ((r0 + 2) & 7)) << 3) | (col & 7))] =
                (unsigned short)w23;
            tile[(r0 + 3) * 256 + ((((col >> 3) ^ ((r0 + 3) & 7)) << 3) | (col & 7))] =
                (unsigned short)(w23 >> 16);
        }
    }
    __syncthreads();

    // ---- GEMM2: rel = h2 @ W3 (same prefetch) ----
    #pragma unroll
    for (int mt = 0; mt < 4; ++mt)
        #pragma unroll
        for (int nt = 0; nt < 4; ++nt) acc[mt][nt] = zero4;
    {
        const unsigned short* bb = w3t + (n0 + lm) * 256 + quad * 8;
        short8 bcur[4], bnxt[4];
        #pragma unroll
        for (int nt = 0; nt < 4; ++nt) bcur[nt] = *(const short8*)(bb + nt * 4096);
        for (int ks = 0; ks < 8; ++ks) {
            if (ks < 7) {
                #pragma unroll
                for (int nt = 0; nt < 4; ++nt)
                    bnxt[nt] = *(const short8*)(bb + nt * 4096 + (ks + 1) * 32);
            }
            const int coff = (((ks * 4 + quad) ^ (lane & 7)) << 3);
            short8 afr[4];
            #pragma unroll
            for (int mt = 0; mt < 4; ++mt)
                afr[mt] = *(const short8*)(&tile[(mt * 16 + lm) * 256 + coff]);
            #pragma unroll
            for (int mt = 0; mt < 4; ++mt)
                #pragma unroll
                for (int nt = 0; nt < 4; ++nt)
                    acc[mt][nt] = __builtin_amdgcn_mfma_f32_16x16x32_bf16(
                        afr[mt], bcur[nt], acc[mt][nt], 0, 0, 0);
            #pragma unroll
            for (int nt = 0; nt < 4; ++nt) bcur[nt] = bnxt[nt];
        }
    }

    // ---- relu + row-sum over 64 pairs -> atomicAdd into summed[b][d] ----
    #pragma unroll
    for (int nt = 0; nt < 4; ++nt) {
        float s = 0.f;
        #pragma unroll
        for (int mt = 0; mt < 4; ++mt)
            #pragma unroll
            for (int rg = 0; rg < 4; ++rg)
                s += fmaxf(acc[mt][nt][rg] + b3c[nt], 0.f);
        s += __shfl_xor(s, 16);
        s += __shfl_xor(s, 32);
        if (quad == 0)
            atomicAdd(&summed[b * 256 + n0 + nt * 16 + lm], s);
    }
}

// ---- f_phi (fp32), 1024 threads: 4-way k-split per 256-wide layer -------
__global__ __launch_bounds__(1024) void k_tail(
    const float* __restrict__ summed,
    const float* __restrict__ fw1, const float* __restrict__ fb1,
    const float* __restrict__ fw2, const float* __restrict__ fb2,
    const float* __restrict__ fw3, const float* __restrict__ fb3,
    float* __restrict__ out)
{
    __shared__ float s0[256], s1[256], red[1024];
    const int b = blockIdx.x, tid = threadIdx.x;
    const int d = tid & 255, kh = tid >> 8;     // kh 0..3
    if (tid < 256) s0[tid] = summed[b * 256 + tid];
    __syncthreads();
    float p = 0.f;
    #pragma unroll 16
    for (int k = kh * 64; k < kh * 64 + 64; ++k) p += s0[k] * fw1[k * 256 + d];
    red[kh * 256 + d] = p;
    __syncthreads();
    if (tid < 256)
        s1[tid] = fmaxf(red[tid] + red[256 + tid] + red[512 + tid] + red[768 + tid]
                        + fb1[tid], 0.f);
    __syncthreads();
    p = 0.f;
    #pragma unroll 16
    for (int k = kh * 64; k < kh * 64 + 64; ++k) p += s1[k] * fw2[k * 256 + d];
    red[kh * 256 + d] = p;
    __syncthreads();
    if (tid < 256)
        s0[tid] = fmaxf(red[tid] + red[256 + tid] + red[512 + tid] + red[768 + tid]
                        + fb2[tid], 0.f);
    __syncthreads();
    const int d3 = tid & 31, kh3 = tid >> 5;    // kh3 0..31
    p = 0.f;
    #pragma unroll
    for (int k = kh3 * 8; k < kh3 * 8 + 8; ++k) p += s0[k] * fw3[k * 32 + d3];
    red[kh3 * 32 + d3] = p;
    __syncthreads();
    if (tid < 32) {
        float o = fb3[tid];
        #pragma unroll 8
        for (int r = 0; r < 32; ++r) o += red[r * 32 + tid];
        out[b * 32 + tid] = o;
    }
}

extern "C" void kernel_launch(void* const* d_in, const int* in_sizes, int n_in,
                              void* d_out, int out_size, void* d_ws, size_t ws_size,
                              hipStream_t stream) {
    const float* x    = (const float*)d_in[0];
    const float* code = (const float*)d_in[1];
    const float* gw1  = (const float*)d_in[2];
    const float* gb1  = (const float*)d_in[3];
    const float* gw2  = (const float*)d_in[4];
    const float* gb2  = (const float*)d_in[5];
    const float* gw3  = (const float*)d_in[6];
    const float* gb3  = (const float*)d_in[7];
    const float* fw1  = (const float*)d_in[8];
    const float* fb1  = (const float*)d_in[9];
    const float* fw2  = (const float*)d_in[10];
    const float* fb2  = (const float*)d_in[11];
    const float* fw3  = (const float*)d_in[12];
    const float* fb3  = (const float*)d_in[13];
    float* out = (float*)d_out;

    // workspace layout (bytes), total ~2.27 MB
    char* ws = (char*)d_ws;
    unsigned short* ub  = (unsigned short*)(ws);               // 1 MiB
    unsigned short* vb  = (unsigned short*)(ws + 1048576);     // 1 MiB
    unsigned short* w2t = (unsigned short*)(ws + 2097152);     // 128 KiB
    unsigned short* w3t = (unsigned short*)(ws + 2228224);     // 128 KiB
    float* summed = (float*)(ws + 2359296);                    // 8 KiB

    hipLaunchKernelGGL(k_pre, dim3(33, 8), dim3(256), 0, stream,
                       x, code, gw1, gb1, gw2, gw3, ub, vb, w2t, w3t, summed);
    hipLaunchKernelGGL(k_main, dim3(NTILE, 8), dim3(256), 0, stream,
                       ub, vb, w2t, w3t, gb2, gb3, summed);
    hipLaunchKernelGGL(k_tail, dim3(8), dim3(1024), 0, stream,
                       summed, fw1, fb1, fw2, fb2, fw3, fb3, out);
}